// Round 10
// baseline (48127.200 us; speedup 1.0000x reference)
//
#include <hip/hip_runtime.h>
#include <cmath>

#define HID   512
#define VOCAB 100
#define G3    1536            // 3*HID
#define GEXT  1664            // G3 + 100 logits + 28 pad (104 tiles of 16)
#define NT    104             // column tiles of 16
#define TMAX  201
#define BLOCK 512             // 8 waves
#define NWG   256
#define NGRP  8               // row groups (intended: 1 per XCD via bid&7)
#define GBLK  32              // blocks per group
#define NCS   26              // compute slices per group (26*4 = 104 tiles)
#define TPS   4               // tiles per compute slice
#define RPB   8               // rows updated per block

typedef __bf16 bf16x8 __attribute__((ext_vector_type(8)));
typedef float  f32x4  __attribute__((ext_vector_type(4)));

// ---- workspace layout (float offsets) ----
#define SZ_WPK   (NT * 16 * 2 * 64 * 8)   // bf16 count: packed B-fragments (3.4 MB)
#define FBASE    (SZ_WPK / 2)
#define OFF_EIH  FBASE                    // E_ih [100][1536] f32
#define SZ_EIH   (VOCAB * G3)
#define OFF_WIHT (OFF_EIH + SZ_EIH)       // W_ih^T [512][1536] f32 (eih_kernel input)
#define SZ_WIHT  (HID * G3)
#define OFF_BEXT (OFF_WIHT + SZ_WIHT)     // [b_hh | b_proj | pad] f32
#define OFF_GH   (OFF_BEXT + GEXT)        // gh buffer [2048][GEXT] f32 (13.6 MB)
#define SZ_GH    (2048 * GEXT)
#define OFF_HF   (OFF_GH + SZ_GH)         // h A-fragments: 8 grp * 32 rt * 16 ks * 64 lanes * 16B
#define SZ_HF    (NGRP * 32 * 16 * 64 * 4)
#define OFF_FLG  (OFF_HF + SZ_HF)         // 16 ints: flag_h[8], flag_gh[8]
// total ~25 MB

__global__ void prep_kernel(const float* __restrict__ W_ih,
                            const float* __restrict__ b_hh,
                            const float* __restrict__ b_proj,
                            float* __restrict__ ws)
{
  int idx = blockIdx.x * 256 + threadIdx.x;
  if (idx < SZ_WIHT) {
    int k = idx / G3, j = idx - k * G3;
    ws[OFF_WIHT + idx] = W_ih[j * HID + k];
  } else if (idx < SZ_WIHT + GEXT) {
    int j = idx - SZ_WIHT;
    float v = 0.f;
    if (j < G3)              v = b_hh[j];
    else if (j < G3 + VOCAB) v = b_proj[j - G3];
    ws[OFF_BEXT + j] = v;
  }
}

// Pack W into split-bf16 MFMA B-fragments (identical layout to rounds 4-8).
// frag index = tile*2048 + ks*128 + half*64 + lane; 8 bf16 per frag.
__global__ void pack_kernel(const float* __restrict__ W_hh,
                            const float* __restrict__ W_proj,
                            __bf16* __restrict__ wpk)
{
  int idx = blockIdx.x * 256 + threadIdx.x;
  if (idx >= NT * 16 * 64 * 8) return;
  int j    = idx & 7;
  int lane = (idx >> 3) & 63;
  int ks   = (idx >> 9) & 15;
  int c    = idx >> 13;
  int col  = c * 16 + (lane & 15);
  int k    = ks * 32 + (lane >> 4) * 8 + j;
  float w = 0.f;
  if (col < G3)              w = W_hh[col * HID + k];
  else if (col < G3 + VOCAB) w = W_proj[(col - G3) * HID + k];
  __bf16 hi = (__bf16)w;
  __bf16 lo = (__bf16)(w - (float)hi);
  int base = (((c * 16 + ks) * 2) * 64 + lane) * 8 + j;
  wpk[base]       = hi;
  wpk[base + 512] = lo;
}

__global__ void eih_kernel(const float* __restrict__ embed,
                           const float* __restrict__ b_ih,
                           float* __restrict__ ws)
{
  int v = blockIdx.x / 6;
  int j = (blockIdx.x % 6) * 256 + threadIdx.x;
  const float* WihT = ws + OFF_WIHT;
  const float* e = embed + v * HID;
  float acc = b_ih[j];
  for (int k = 0; k < HID; ++k)
    acc = fmaf(WihT[k * G3 + j], e[k], acc);
  ws[OFF_EIH + v * G3 + j] = acc;
}

__global__ void zero_flags(float* ws) {
  if (threadIdx.x < 16) ((int*)(ws + OFF_FLG))[threadIdx.x] = 0;
}

__device__ __forceinline__ void wait_flag(int* f, int target) {
  long it = 0;
  while (__hip_atomic_load(f, __ATOMIC_ACQUIRE, __HIP_MEMORY_SCOPE_AGENT) < target) {
    __builtin_amdgcn_s_sleep(2);
    if (++it > 100000000L) break;   // terminate rather than wedge on protocol bug
  }
}

// Persistent cooperative GRU decode.
// Group g (bid&7, XCD-pinned under %8 round-robin) owns rows [g*256, g*256+256).
// Block i<26 of the group: weight slice (4 tiles, 128 KB) LDS-resident; computes
// gh[256 rows x 64 cols] each step from global h-fragments. All 32 blocks:
// update their own 8 rows (argmax, gates, logits, h-frag writeback).
// Sync: per-group flag counters, agent-scope acquire/release + __threadfence.
__global__ __launch_bounds__(BLOCK, 2) void decode_kernel(
    const float* __restrict__ feat,
    const int* __restrict__ sos,
    float* __restrict__ wsf,
    const __bf16* __restrict__ wpk,
    float* __restrict__ out)
{
  __shared__ bf16x8 ldsB[8192];                 // 128 KB: 4 tiles * 16 ks * 2 halves * 64 lanes
  __shared__ unsigned short stage_us[8192];     // 16 KB h-frag staging tile
  __shared__ int pred_lds[RPB];

  const float* __restrict__ EIH  = wsf + OFF_EIH;
  const float* __restrict__ bext = wsf + OFF_BEXT;
  float* __restrict__ ghp  = wsf + OFF_GH;
  bf16x8* __restrict__ hfB = (bf16x8*)(wsf + OFF_HF);
  int* flag_h  = (int*)(wsf + OFF_FLG);
  int* flag_gh = flag_h + 8;

  const int tid  = threadIdx.x;
  const int lane = tid & 63;
  const int wv   = tid >> 6;            // wave 0..7
  const int g    = blockIdx.x & 7;      // group (intended XCD)
  const int i    = blockIdx.x >> 3;     // index in group 0..31
  const bool is_compute = (i < NCS);
  const int rowbase = g * 256 + i * RPB;   // this block's 8 update rows

  // ---- load LDS weight slice (once) ----
  if (is_compute) {
    const bf16x8* wsrc = ((const bf16x8*)wpk) + (size_t)(i * TPS) * 2048;
    for (int f = tid; f < 8192; f += BLOCK) ldsB[f] = wsrc[f];
  }
  if (tid < RPB) pred_lds[tid] = sos[0];

  // ---- init (t = -1): h = feat for my 8 rows; write h-fragments ----
  const int u = tid;                    // unit 0..511
  float h[RPB];
  {
    const int ks_ = u >> 5, kl = u & 31, lhi = ((kl >> 3) << 4), j2 = u & 7;
    #pragma unroll
    for (int r = 0; r < RPB; ++r) {
      float f = feat[(size_t)(rowbase + r) * HID + u];
      h[r] = f;
      __bf16 hi = (__bf16)f;
      __bf16 lo = (__bf16)(f - (float)hi);
      stage_us[(ks_ * 64 + (lhi | r)) * 8 + j2]       = __builtin_bit_cast(unsigned short, hi);
      stage_us[(ks_ * 64 + (lhi | (r + 8))) * 8 + j2] = __builtin_bit_cast(unsigned short, lo);
    }
  }
  __syncthreads();
  {
    float4* dst = (float4*)(hfB + (size_t)(g * 32 + i) * 1024);
    const float4* src = (const float4*)stage_us;
    for (int f = tid; f < 1024; f += BLOCK) dst[f] = src[f];
  }
  __threadfence();
  __syncthreads();
  if (tid == 0) __hip_atomic_fetch_add(flag_h + g, 1, __ATOMIC_RELEASE, __HIP_MEMORY_SCOPE_AGENT);

  // per-thread consumer biases
  const float gbr = bext[u], gbz = bext[HID + u], gbn = bext[2 * HID + u];
  const float ab0 = (lane < VOCAB)      ? bext[G3 + lane]      : 0.f;
  const float ab1 = (lane + 64 < VOCAB) ? bext[G3 + 64 + lane] : 0.f;

  for (int t = 0; t <= TMAX; ++t) {
    // ================= phase 1: gh = h @ W (compute blocks) =================
    if (is_compute) {
      bool do_mfma = (t < TMAX) || (i >= 24);   // at TMAX only logits slices matter
      if (do_mfma) {
        if (tid == 0) wait_flag(flag_h + g, GBLK * (t + 1));
        __syncthreads();
        __threadfence();   // acquire: invalidate caches before reading h-frags

        const bf16x8* hfg = hfB + (size_t)(g * 32) * 1024;
        #pragma unroll
        for (int rp = 0; rp < 2; ++rp) {
          const int rtA = wv + rp * 16, rtB = rtA + 8;
          bf16x8 aA[16], aB[16];
          #pragma unroll
          for (int ks = 0; ks < 16; ++ks) {
            aA[ks] = hfg[(size_t)rtA * 1024 + ks * 64 + lane];
            aB[ks] = hfg[(size_t)rtB * 1024 + ks * 64 + lane];
          }
          for (int ct = 0; ct < TPS; ++ct) {
            f32x4 accA = {0.f, 0.f, 0.f, 0.f}, accB = {0.f, 0.f, 0.f, 0.f};
            #pragma unroll
            for (int ks = 0; ks < 16; ++ks) {
              bf16x8 bh = ldsB[ct * 2048 + ks * 128 + lane];
              bf16x8 bl = ldsB[ct * 2048 + ks * 128 + 64 + lane];
              accA = __builtin_amdgcn_mfma_f32_16x16x32_bf16(aA[ks], bh, accA, 0, 0, 0);
              accA = __builtin_amdgcn_mfma_f32_16x16x32_bf16(aA[ks], bl, accA, 0, 0, 0);
              accB = __builtin_amdgcn_mfma_f32_16x16x32_bf16(aB[ks], bh, accB, 0, 0, 0);
              accB = __builtin_amdgcn_mfma_f32_16x16x32_bf16(aB[ks], bl, accB, 0, 0, 0);
            }
            // fold H_lo rows (8-15) into H_hi rows (0-7), write gh stripe
            const int colw = (i * TPS + ct) * 16 + (lane & 15);
            float vsA[4], vsB[4];
            #pragma unroll
            for (int q = 0; q < 4; ++q) {
              vsA[q] = accA[q] + __shfl_xor(accA[q], 32, 64);
              vsB[q] = accB[q] + __shfl_xor(accB[q], 32, 64);
            }
            if (lane < 32) {
              const int r0 = (lane >> 4) * 4;
              #pragma unroll
              for (int q = 0; q < 4; ++q) {
                ghp[(size_t)(g * 256 + rtA * 8 + r0 + q) * GEXT + colw] = vsA[q];
                ghp[(size_t)(g * 256 + rtB * 8 + r0 + q) * GEXT + colw] = vsB[q];
              }
            }
          }
        }
        __threadfence();   // release gh writes
        __syncthreads();
      }
      if (tid == 0) __hip_atomic_fetch_add(flag_gh + g, 1, __ATOMIC_RELEASE, __HIP_MEMORY_SCOPE_AGENT);
    }

    // ================= phase 2: update my 8 rows (all blocks) =================
    if (tid == 0) wait_flag(flag_gh + g, NCS * (t + 1));
    __syncthreads();
    __threadfence();   // acquire gh

    if (t >= 1) {
      for (int e = tid; e < RPB * VOCAB; e += BLOCK) {
        int r = e / VOCAB, v = e - r * VOCAB;
        float lg = ghp[(size_t)(rowbase + r) * GEXT + G3 + v] + bext[G3 + v];
        __builtin_nontemporal_store(
            lg, &out[((size_t)(rowbase + r) * VOCAB + v) * TMAX + (t - 1)]);
      }
      if (t < TMAX) {   // wave wv: argmax of row wv (first-max semantics)
        const size_t gr = (size_t)(rowbase + wv) * GEXT + G3;
        float v0 = (lane < VOCAB)      ? ghp[gr + lane] + ab0      : -1e30f;
        float v1 = (lane + 64 < VOCAB) ? ghp[gr + 64 + lane] + ab1 : -1e30f;
        float bv; int bi;
        if (v0 >= v1) { bv = v0; bi = lane; } else { bv = v1; bi = lane + 64; }
        #pragma unroll
        for (int off = 32; off >= 1; off >>= 1) {
          float ov = __shfl_xor(bv, off);
          int   oi = __shfl_xor(bi, off);
          if (ov > bv || (ov == bv && oi < bi)) { bv = ov; bi = oi; }
        }
        if (lane == 0) pred_lds[wv] = bi;
      }
    }
    __syncthreads();   // pred ready

    if (t < TMAX) {
      const int ks_ = u >> 5, kl = u & 31, lhi = ((kl >> 3) << 4), j2 = u & 7;
      #pragma unroll
      for (int r = 0; r < RPB; ++r) {
        const float* eb = EIH + (size_t)pred_lds[r] * G3;
        const size_t gr = (size_t)(rowbase + r) * GEXT;
        float srg = eb[u]           + gbr + ghp[gr + u];
        float szg = eb[HID + u]     + gbz + ghp[gr + HID + u];
        float hn  = ghp[gr + 2 * HID + u] + gbn;
        float rg = 1.f / (1.f + expf(-srg));
        float zg = 1.f / (1.f + expf(-szg));
        float ng = tanhf(eb[2 * HID + u] + rg * hn);
        h[r] = (1.f - zg) * ng + zg * h[r];
        __bf16 hi = (__bf16)h[r];
        __bf16 lo = (__bf16)(h[r] - (float)hi);
        stage_us[(ks_ * 64 + (lhi | r)) * 8 + j2]       = __builtin_bit_cast(unsigned short, hi);
        stage_us[(ks_ * 64 + (lhi | (r + 8))) * 8 + j2] = __builtin_bit_cast(unsigned short, lo);
      }
      __syncthreads();
      {
        float4* dst = (float4*)(hfB + (size_t)(g * 32 + i) * 1024);
        const float4* src = (const float4*)stage_us;
        for (int f = tid; f < 1024; f += BLOCK) dst[f] = src[f];
      }
      __threadfence();   // release h-frags
      __syncthreads();
      if (tid == 0) __hip_atomic_fetch_add(flag_h + g, 1, __ATOMIC_RELEASE, __HIP_MEMORY_SCOPE_AGENT);
    }
  }
}

extern "C" void kernel_launch(void* const* d_in, const int* in_sizes, int n_in,
                              void* d_out, int out_size, void* d_ws, size_t ws_size,
                              hipStream_t stream)
{
  const float* feat   = (const float*)d_in[0];
  const float* W_ih   = (const float*)d_in[1];
  const float* W_hh   = (const float*)d_in[2];
  const float* b_ih   = (const float*)d_in[3];
  const float* b_hh   = (const float*)d_in[4];
  const float* W_proj = (const float*)d_in[5];
  const float* b_proj = (const float*)d_in[6];
  const float* embed  = (const float*)d_in[7];
  const int*   sos    = (const int*)d_in[8];

  float*  wsf = (float*)d_ws;
  __bf16* wpk = (__bf16*)d_ws;
  float*  out = (float*)d_out;

  const int prep_total = SZ_WIHT + GEXT;
  prep_kernel<<<(prep_total + 255) / 256, 256, 0, stream>>>(W_ih, b_hh, b_proj, wsf);
  pack_kernel<<<(NT * 16 * 64 * 8 + 255) / 256, 256, 0, stream>>>(W_hh, W_proj, wpk);
  eih_kernel<<<600, 256, 0, stream>>>(embed, b_ih, wsf);
  zero_flags<<<1, 64, 0, stream>>>(wsf);
  decode_kernel<<<NWG, BLOCK, 0, stream>>>(feat, sos, wsf, wpk, out);
}

// Round 11
// 47342.822 us; speedup vs baseline: 1.0166x; 1.0166x over previous
//
#include <hip/hip_runtime.h>
#include <cmath>

#define HID   512
#define VOCAB 100
#define G3    1536            // 3*HID
#define GEXT  1664            // G3 + 100 logits + 28 pad (104 tiles of 16)
#define NT    104             // column tiles of 16
#define TMAX  201
#define BLOCK 512             // 8 waves
#define NWG   256
#define NGRP  8               // row groups (intended: 1 per XCD via bid&7)
#define GBLK  32              // blocks per group
#define NCS   26              // compute slices per group (26*4 = 104 tiles)
#define TPS   4               // tiles per compute slice
#define RPB   8               // rows updated per block

typedef __bf16 bf16x8 __attribute__((ext_vector_type(8)));
typedef float  f32x4  __attribute__((ext_vector_type(4)));

// ---- workspace layout (float offsets) ----
#define SZ_WPK   (NT * 16 * 2 * 64 * 8)   // bf16 count: packed B-fragments (3.4 MB)
#define FBASE    (SZ_WPK / 2)
#define OFF_EIH  FBASE                    // E_ih [100][1536] f32
#define SZ_EIH   (VOCAB * G3)
#define OFF_WIHT (OFF_EIH + SZ_EIH)       // W_ih^T [512][1536] f32 (eih_kernel input)
#define SZ_WIHT  (HID * G3)
#define OFF_BEXT (OFF_WIHT + SZ_WIHT)     // [b_hh | b_proj | pad] f32
#define OFF_GH   (OFF_BEXT + GEXT)        // gh buffer [2048][GEXT] f32 (13.6 MB)
#define SZ_GH    (2048 * GEXT)
#define OFF_HF   (OFF_GH + SZ_GH)         // h A-fragments: 8 grp * 32 rt * 16 ks * 64 lanes * 16B
#define SZ_HF    (NGRP * 32 * 16 * 64 * 4)
#define OFF_FLG  (OFF_HF + SZ_HF)         // 16 ints: flag_h[8], flag_gh[8]
// total ~25 MB

__global__ void prep_kernel(const float* __restrict__ W_ih,
                            const float* __restrict__ b_hh,
                            const float* __restrict__ b_proj,
                            float* __restrict__ ws)
{
  int idx = blockIdx.x * 256 + threadIdx.x;
  if (idx < SZ_WIHT) {
    int k = idx / G3, j = idx - k * G3;
    ws[OFF_WIHT + idx] = W_ih[j * HID + k];
  } else if (idx < SZ_WIHT + GEXT) {
    int j = idx - SZ_WIHT;
    float v = 0.f;
    if (j < G3)              v = b_hh[j];
    else if (j < G3 + VOCAB) v = b_proj[j - G3];
    ws[OFF_BEXT + j] = v;
  }
}

// Pack W into split-bf16 MFMA B-fragments (identical layout to rounds 4-8).
// frag index = tile*2048 + ks*128 + half*64 + lane; 8 bf16 per frag.
__global__ void pack_kernel(const float* __restrict__ W_hh,
                            const float* __restrict__ W_proj,
                            __bf16* __restrict__ wpk)
{
  int idx = blockIdx.x * 256 + threadIdx.x;
  if (idx >= NT * 16 * 64 * 8) return;
  int j    = idx & 7;
  int lane = (idx >> 3) & 63;
  int ks   = (idx >> 9) & 15;
  int c    = idx >> 13;
  int col  = c * 16 + (lane & 15);
  int k    = ks * 32 + (lane >> 4) * 8 + j;
  float w = 0.f;
  if (col < G3)              w = W_hh[col * HID + k];
  else if (col < G3 + VOCAB) w = W_proj[(col - G3) * HID + k];
  __bf16 hi = (__bf16)w;
  __bf16 lo = (__bf16)(w - (float)hi);
  int base = (((c * 16 + ks) * 2) * 64 + lane) * 8 + j;
  wpk[base]       = hi;
  wpk[base + 512] = lo;
}

__global__ void eih_kernel(const float* __restrict__ embed,
                           const float* __restrict__ b_ih,
                           float* __restrict__ ws)
{
  int v = blockIdx.x / 6;
  int j = (blockIdx.x % 6) * 256 + threadIdx.x;
  const float* WihT = ws + OFF_WIHT;
  const float* e = embed + v * HID;
  float acc = b_ih[j];
  for (int k = 0; k < HID; ++k)
    acc = fmaf(WihT[k * G3 + j], e[k], acc);
  ws[OFF_EIH + v * G3 + j] = acc;
}

__global__ void zero_flags(float* ws) {
  if (threadIdx.x < 16) ((int*)(ws + OFF_FLG))[threadIdx.x] = 0;
}

__device__ __forceinline__ void wait_flag(int* f, int target) {
  long it = 0;
  while (__hip_atomic_load(f, __ATOMIC_ACQUIRE, __HIP_MEMORY_SCOPE_AGENT) < target) {
    __builtin_amdgcn_s_sleep(2);
    if (++it > 100000000L) break;   // terminate rather than wedge on protocol bug
  }
}

// Persistent cooperative GRU decode.
// Group g (bid&7, XCD-pinned under %8 round-robin) owns rows [g*256, g*256+256).
// Block i<26 of the group: weight slice (4 tiles, 128 KB) LDS-resident; computes
// gh[256 rows x 64 cols] each step from global h-fragments. All 32 blocks:
// update their own 8 rows (argmax, gates, logits, h-frag writeback).
// Sync: per-group flag counters, agent-scope acquire/release + __threadfence.
__global__ __launch_bounds__(BLOCK, 2) void decode_kernel(
    const float* __restrict__ feat,
    const int* __restrict__ sos,
    float* __restrict__ wsf,
    const __bf16* __restrict__ wpk,
    float* __restrict__ out)
{
  __shared__ bf16x8 ldsB[8192];                 // 128 KB: 4 tiles * 16 ks * 2 halves * 64 lanes
  __shared__ unsigned short stage_us[8192];     // 16 KB h-frag staging tile
  __shared__ int pred_lds[RPB];

  const float* __restrict__ EIH  = wsf + OFF_EIH;
  const float* __restrict__ bext = wsf + OFF_BEXT;
  float* __restrict__ ghp  = wsf + OFF_GH;
  bf16x8* __restrict__ hfB = (bf16x8*)(wsf + OFF_HF);
  int* flag_h  = (int*)(wsf + OFF_FLG);
  int* flag_gh = flag_h + 8;

  const int tid  = threadIdx.x;
  const int lane = tid & 63;
  const int wv   = tid >> 6;            // wave 0..7
  const int g    = blockIdx.x & 7;      // group (intended XCD)
  const int i    = blockIdx.x >> 3;     // index in group 0..31
  const bool is_compute = (i < NCS);
  const int rowbase = g * 256 + i * RPB;   // this block's 8 update rows

  // ---- load LDS weight slice (once) ----
  if (is_compute) {
    const bf16x8* wsrc = ((const bf16x8*)wpk) + (size_t)(i * TPS) * 2048;
    for (int f = tid; f < 8192; f += BLOCK) ldsB[f] = wsrc[f];
  }
  if (tid < RPB) pred_lds[tid] = sos[0];

  // ---- init (t = -1): h = feat for my 8 rows; write h-fragments ----
  const int u = tid;                    // unit 0..511
  float h[RPB];
  {
    const int ks_ = u >> 5, kl = u & 31, lhi = ((kl >> 3) << 4), j2 = u & 7;
    #pragma unroll
    for (int r = 0; r < RPB; ++r) {
      float f = feat[(size_t)(rowbase + r) * HID + u];
      h[r] = f;
      __bf16 hi = (__bf16)f;
      __bf16 lo = (__bf16)(f - (float)hi);
      stage_us[(ks_ * 64 + (lhi | r)) * 8 + j2]       = __builtin_bit_cast(unsigned short, hi);
      stage_us[(ks_ * 64 + (lhi | (r + 8))) * 8 + j2] = __builtin_bit_cast(unsigned short, lo);
    }
  }
  __syncthreads();
  {
    float4* dst = (float4*)(hfB + (size_t)(g * 32 + i) * 1024);
    const float4* src = (const float4*)stage_us;
    for (int f = tid; f < 1024; f += BLOCK) dst[f] = src[f];
  }
  __threadfence();
  __syncthreads();
  if (tid == 0) __hip_atomic_fetch_add(flag_h + g, 1, __ATOMIC_RELEASE, __HIP_MEMORY_SCOPE_AGENT);

  // per-thread consumer biases
  const float gbr = bext[u], gbz = bext[HID + u], gbn = bext[2 * HID + u];
  const float ab0 = (lane < VOCAB)      ? bext[G3 + lane]      : 0.f;
  const float ab1 = (lane + 64 < VOCAB) ? bext[G3 + 64 + lane] : 0.f;

  for (int t = 0; t <= TMAX; ++t) {
    // ================= phase 1: gh = h @ W (compute blocks) =================
    if (is_compute) {
      bool do_mfma = (t < TMAX) || (i >= 24);   // at TMAX only logits slices matter
      if (do_mfma) {
        if (tid == 0) wait_flag(flag_h + g, GBLK * (t + 1));
        __syncthreads();
        __threadfence();   // acquire: invalidate caches before reading h-frags

        const bf16x8* hfg = hfB + (size_t)(g * 32) * 1024;
        #pragma unroll
        for (int rp = 0; rp < 2; ++rp) {
          const int rtA = wv + rp * 16, rtB = rtA + 8;
          bf16x8 aA[16], aB[16];
          #pragma unroll
          for (int ks = 0; ks < 16; ++ks) {
            aA[ks] = hfg[(size_t)rtA * 1024 + ks * 64 + lane];
            aB[ks] = hfg[(size_t)rtB * 1024 + ks * 64 + lane];
          }
          for (int ct = 0; ct < TPS; ++ct) {
            f32x4 accA = {0.f, 0.f, 0.f, 0.f}, accB = {0.f, 0.f, 0.f, 0.f};
            #pragma unroll
            for (int ks = 0; ks < 16; ++ks) {
              bf16x8 bh = ldsB[ct * 2048 + ks * 128 + lane];
              bf16x8 bl = ldsB[ct * 2048 + ks * 128 + 64 + lane];
              accA = __builtin_amdgcn_mfma_f32_16x16x32_bf16(aA[ks], bh, accA, 0, 0, 0);
              accA = __builtin_amdgcn_mfma_f32_16x16x32_bf16(aA[ks], bl, accA, 0, 0, 0);
              accB = __builtin_amdgcn_mfma_f32_16x16x32_bf16(aB[ks], bh, accB, 0, 0, 0);
              accB = __builtin_amdgcn_mfma_f32_16x16x32_bf16(aB[ks], bl, accB, 0, 0, 0);
            }
            // fold H_lo rows (8-15) into H_hi rows (0-7), write gh stripe
            const int colw = (i * TPS + ct) * 16 + (lane & 15);
            float vsA[4], vsB[4];
            #pragma unroll
            for (int q = 0; q < 4; ++q) {
              vsA[q] = accA[q] + __shfl_xor(accA[q], 32, 64);
              vsB[q] = accB[q] + __shfl_xor(accB[q], 32, 64);
            }
            if (lane < 32) {
              const int r0 = (lane >> 4) * 4;
              #pragma unroll
              for (int q = 0; q < 4; ++q) {
                ghp[(size_t)(g * 256 + rtA * 8 + r0 + q) * GEXT + colw] = vsA[q];
                ghp[(size_t)(g * 256 + rtB * 8 + r0 + q) * GEXT + colw] = vsB[q];
              }
            }
          }
        }
        __threadfence();   // release gh writes
        __syncthreads();
      }
      if (tid == 0) __hip_atomic_fetch_add(flag_gh + g, 1, __ATOMIC_RELEASE, __HIP_MEMORY_SCOPE_AGENT);
    }

    // ================= phase 2: update my 8 rows (all blocks) =================
    if (tid == 0) wait_flag(flag_gh + g, NCS * (t + 1));
    __syncthreads();
    __threadfence();   // acquire gh

    if (t >= 1) {
      for (int e = tid; e < RPB * VOCAB; e += BLOCK) {
        int r = e / VOCAB, v = e - r * VOCAB;
        float lg = ghp[(size_t)(rowbase + r) * GEXT + G3 + v] + bext[G3 + v];
        __builtin_nontemporal_store(
            lg, &out[((size_t)(rowbase + r) * VOCAB + v) * TMAX + (t - 1)]);
      }
      if (t < TMAX) {   // wave wv: argmax of row wv (first-max semantics)
        const size_t gr = (size_t)(rowbase + wv) * GEXT + G3;
        float v0 = (lane < VOCAB)      ? ghp[gr + lane] + ab0      : -1e30f;
        float v1 = (lane + 64 < VOCAB) ? ghp[gr + 64 + lane] + ab1 : -1e30f;
        float bv; int bi;
        if (v0 >= v1) { bv = v0; bi = lane; } else { bv = v1; bi = lane + 64; }
        #pragma unroll
        for (int off = 32; off >= 1; off >>= 1) {
          float ov = __shfl_xor(bv, off);
          int   oi = __shfl_xor(bi, off);
          if (ov > bv || (ov == bv && oi < bi)) { bv = ov; bi = oi; }
        }
        if (lane == 0) pred_lds[wv] = bi;
      }
    }
    __syncthreads();   // pred ready

    if (t < TMAX) {
      const int ks_ = u >> 5, kl = u & 31, lhi = ((kl >> 3) << 4), j2 = u & 7;
      #pragma unroll
      for (int r = 0; r < RPB; ++r) {
        const float* eb = EIH + (size_t)pred_lds[r] * G3;
        const size_t gr = (size_t)(rowbase + r) * GEXT;
        float srg = eb[u]           + gbr + ghp[gr + u];
        float szg = eb[HID + u]     + gbz + ghp[gr + HID + u];
        float hn  = ghp[gr + 2 * HID + u] + gbn;
        float rg = 1.f / (1.f + expf(-srg));
        float zg = 1.f / (1.f + expf(-szg));
        float ng = tanhf(eb[2 * HID + u] + rg * hn);
        h[r] = (1.f - zg) * ng + zg * h[r];
        __bf16 hi = (__bf16)h[r];
        __bf16 lo = (__bf16)(h[r] - (float)hi);
        stage_us[(ks_ * 64 + (lhi | r)) * 8 + j2]       = __builtin_bit_cast(unsigned short, hi);
        stage_us[(ks_ * 64 + (lhi | (r + 8))) * 8 + j2] = __builtin_bit_cast(unsigned short, lo);
      }
      __syncthreads();
      {
        float4* dst = (float4*)(hfB + (size_t)(g * 32 + i) * 1024);
        const float4* src = (const float4*)stage_us;
        for (int f = tid; f < 1024; f += BLOCK) dst[f] = src[f];
      }
      __threadfence();   // release h-frags
      __syncthreads();
      if (tid == 0) __hip_atomic_fetch_add(flag_h + g, 1, __ATOMIC_RELEASE, __HIP_MEMORY_SCOPE_AGENT);
    }
  }
}

extern "C" void kernel_launch(void* const* d_in, const int* in_sizes, int n_in,
                              void* d_out, int out_size, void* d_ws, size_t ws_size,
                              hipStream_t stream)
{
  const float* feat   = (const float*)d_in[0];
  const float* W_ih   = (const float*)d_in[1];
  const float* W_hh   = (const float*)d_in[2];
  const float* b_ih   = (const float*)d_in[3];
  const float* b_hh   = (const float*)d_in[4];
  const float* W_proj = (const float*)d_in[5];
  const float* b_proj = (const float*)d_in[6];
  const float* embed  = (const float*)d_in[7];
  const int*   sos    = (const int*)d_in[8];

  float*  wsf = (float*)d_ws;
  __bf16* wpk = (__bf16*)d_ws;
  float*  out = (float*)d_out;

  const int prep_total = SZ_WIHT + GEXT;
  prep_kernel<<<(prep_total + 255) / 256, 256, 0, stream>>>(W_ih, b_hh, b_proj, wsf);
  pack_kernel<<<(NT * 16 * 64 * 8 + 255) / 256, 256, 0, stream>>>(W_hh, W_proj, wpk);
  eih_kernel<<<600, 256, 0, stream>>>(embed, b_ih, wsf);
  zero_flags<<<1, 64, 0, stream>>>(wsf);
  decode_kernel<<<NWG, BLOCK, 0, stream>>>(feat, sos, wsf, wpk, out);
}

// Round 13
// 6346.585 us; speedup vs baseline: 7.5832x; 7.4596x over previous
//
#include <hip/hip_runtime.h>
#include <cmath>

#define HID   512
#define VOCAB 100
#define G3    1536            // 3*HID
#define GEXT  1664            // G3 + 100 logits + 28 pad (104 tiles of 16)
#define NT    104             // column tiles of 16
#define TMAX  201
#define ROWS  8
#define BLOCK 1024            // 16 waves: 8 tile-sets x 2 k-halves
#define NWG   256
#define TPW   13              // tiles per tile-set (104/8)
#define GHS   1672            // gh row stride (floats), ==8 mod 32 -> 2-way-free writes

typedef __bf16 bf16x8 __attribute__((ext_vector_type(8)));
typedef float  f32x4  __attribute__((ext_vector_type(4)));
typedef unsigned int u32x4 __attribute__((ext_vector_type(4)));

// ---- workspace layout ----
#define SZ_WPK   (NT * 16 * 2 * 64 * 8)   // bf16: packed B-fragments (3.4 MB)
#define FBASE    (SZ_WPK / 2)
#define OFF_EIH  FBASE                    // E_ih [100][1536] f32
#define SZ_EIH   (VOCAB * G3)
#define OFF_WIHT (OFF_EIH + SZ_EIH)       // W_ih^T [512][1536] f32
#define SZ_WIHT  (HID * G3)
#define OFF_BEXT (OFF_WIHT + SZ_WIHT)     // [b_hh | b_proj | pad] f32

__global__ void prep_kernel(const float* __restrict__ W_ih,
                            const float* __restrict__ b_hh,
                            const float* __restrict__ b_proj,
                            float* __restrict__ ws)
{
  int idx = blockIdx.x * 256 + threadIdx.x;
  if (idx < SZ_WIHT) {
    int k = idx / G3, j = idx - k * G3;
    ws[OFF_WIHT + idx] = W_ih[j * HID + k];
  } else if (idx < SZ_WIHT + GEXT) {
    int j = idx - SZ_WIHT;
    float v = 0.f;
    if (j < G3)              v = b_hh[j];
    else if (j < G3 + VOCAB) v = b_proj[j - G3];
    ws[OFF_BEXT + j] = v;
  }
}

// Pack W (= [W_hh rows | W_proj rows | 0]) into split-bf16 MFMA B-fragments.
// frag index = tile*2048 + ks*128 + (lo?64:0) + lane; 8 bf16 (16 B) per frag.
// Byte offsets: tile*32768 + ks*2048 + (lo?1024:0) + lane*16.
__global__ void pack_kernel(const float* __restrict__ W_hh,
                            const float* __restrict__ W_proj,
                            __bf16* __restrict__ wpk)
{
  int idx = blockIdx.x * 256 + threadIdx.x;
  if (idx >= NT * 16 * 64 * 8) return;
  int j    = idx & 7;
  int lane = (idx >> 3) & 63;
  int ks   = (idx >> 9) & 15;
  int c    = idx >> 13;
  int col  = c * 16 + (lane & 15);
  int k    = ks * 32 + (lane >> 4) * 8 + j;
  float w = 0.f;
  if (col < G3)              w = W_hh[col * HID + k];
  else if (col < G3 + VOCAB) w = W_proj[(col - G3) * HID + k];
  __bf16 hi = (__bf16)w;
  __bf16 lo = (__bf16)(w - (float)hi);
  int base = (((c * 16 + ks) * 2) * 64 + lane) * 8 + j;
  wpk[base]       = hi;
  wpk[base + 512] = lo;
}

__global__ void eih_kernel(const float* __restrict__ embed,
                           const float* __restrict__ b_ih,
                           float* __restrict__ ws)
{
  int v = blockIdx.x / 6;
  int j = (blockIdx.x % 6) * 256 + threadIdx.x;
  const float* WihT = ws + OFF_WIHT;
  const float* e = embed + v * HID;
  float acc = b_ih[j];
  for (int k = 0; k < HID; ++k)
    acc = fmaf(WihT[k * G3 + j], e[k], acc);
  ws[OFF_EIH + v * G3 + j] = acc;
}

// ---- inline-asm B-stream pipeline primitives ----
// One chunk = 4 x 16B loads = 2 k-steps (hi/lo pairs): offsets 0,1024,2048,3072.
// "=&v" EARLY-CLOBBER is load-bearing: outputs are written asynchronously, so
// they must not alias the address pair %4 (round-11 crash: plain "=v" let
// instr 1's in-flight write clobber the address read by instrs 2-4).
#define GLD4(F0, F1, F2, F3, P)                                   \
  asm volatile("global_load_dwordx4 %0, %4, off\n\t"              \
               "global_load_dwordx4 %1, %4, off offset:1024\n\t"  \
               "global_load_dwordx4 %2, %4, off offset:2048\n\t"  \
               "global_load_dwordx4 %3, %4, off offset:3072"      \
               : "=&v"(F0), "=&v"(F1), "=&v"(F2), "=&v"(F3)       \
               : "v"(P))

// Counted wait + scheduling fence (rule #18: MFMA must not hoist above it).
#define VMWAIT(N)                                 \
  do { asm volatile("s_waitcnt vmcnt(" #N ")");   \
       __builtin_amdgcn_sched_barrier(0); } while (0)

#define BC(X) __builtin_bit_cast(bf16x8, X)

// 4 MFMAs: one chunk (2 k-steps, hi then lo) — exact round-7 operand order.
#define MFMA4(ACC, Q0, Q1, Q2, Q3, A0, A1)                                      \
  do {                                                                          \
    ACC = __builtin_amdgcn_mfma_f32_16x16x32_bf16(A0, BC(Q0), ACC, 0, 0, 0);    \
    ACC = __builtin_amdgcn_mfma_f32_16x16x32_bf16(A0, BC(Q1), ACC, 0, 0, 0);    \
    ACC = __builtin_amdgcn_mfma_f32_16x16x32_bf16(A1, BC(Q2), ACC, 0, 0, 0);    \
    ACC = __builtin_amdgcn_mfma_f32_16x16x32_bf16(A1, BC(Q3), ACC, 0, 0, 0);    \
  } while (0)

// Fold H_lo rows (8-15, lanes 32-63) into H_hi rows and write one gh stripe.
#define FOLDWRITE(ACC, TILE)                                      \
  do {                                                            \
    int colw_ = (TILE) * 16 + (lane & 15);                        \
    float vs_[4];                                                 \
    _Pragma("unroll")                                             \
    for (int i_ = 0; i_ < 4; ++i_)                                \
      vs_[i_] = ACC[i_] + __shfl_xor(ACC[i_], 32, 64);            \
    if (lane < 32) {                                              \
      int r0_ = (lane >> 4) * 4;                                  \
      _Pragma("unroll")                                           \
      for (int i_ = 0; i_ < 4; ++i_)                              \
        ghW[r0_ + i_][colw_] = vs_[i_];                           \
    }                                                             \
  } while (0)

// Persistent GRU decode: 8 rows/block, 256 blocks, 16 waves (8 tile-sets x 2
// k-halves -> ghA/ghB partials). B-stream: inline-asm software pipeline at
// chunk (4-load) depth, 2 rotating register buffers, steady-state vmcnt(4) —
// never drains to 0 until the final chunk of the last tile. MFMA order is
// bit-identical to round 7.
__global__ __launch_bounds__(BLOCK) void decode_kernel(
    const float* __restrict__ feat,
    const int* __restrict__ sos,
    const float* __restrict__ ws,
    const __bf16* __restrict__ wpk,
    float* __restrict__ out)
{
  __shared__ __align__(16) char hab[16 * 1024];   // rows 0-7 hi, 8-15 lo; XOR-swizzled
  __shared__ float ghA[ROWS][GHS];                // k-half 0 partials
  __shared__ float ghB[ROWS][GHS];                // k-half 1 partials
  __shared__ int   pred_lds[ROWS];

  const float* __restrict__ EIH  = ws + OFF_EIH;
  const float* __restrict__ bext = ws + OFF_BEXT;

  const int tid  = threadIdx.x;
  const int lane = tid & 63;
  const int wv   = tid >> 6;          // wave 0..15
  const int half = wv >> 3;           // k-half 0/1
  const int wt   = wv & 7;            // tile-set 0..7
  const int b0   = blockIdx.x * ROWS;
  const int u    = tid & (HID - 1);   // unit 0..511
  const int rb   = (tid >> 9) * 4;    // row base 0 or 4

  float (*ghW)[GHS] = half ? ghB : ghA;

  // ---- init: h in regs (4 rows per thread), split-bf16 into hab ----
  float h[4];
  #pragma unroll
  for (int rr = 0; rr < 4; ++rr) {
    int r = rb + rr;
    float f = feat[(size_t)(b0 + r) * HID + u];
    h[rr] = f;
    __bf16 hi = (__bf16)f;
    __bf16 lo = (__bf16)(f - (float)hi);
    unsigned so = ((unsigned)(u * 2)) ^ (((unsigned)(r & 7)) << 4);
    *(__bf16*)(hab + (r << 10) + so)       = hi;
    *(__bf16*)(hab + ((r + 8) << 10) + so) = lo;
  }
  if (tid < ROWS) pred_lds[tid] = sos[0];
  __syncthreads();

  // per-thread consumer biases
  const float gbr = bext[u], gbz = bext[HID + u], gbn = bext[2 * HID + u];
  const int sr = tid / VOCAB, sv = tid - sr * VOCAB;
  float* outp = nullptr; float outb = 0.f;
  if (tid < ROWS * VOCAB) {
    outp = out + ((size_t)(b0 + sr) * VOCAB + sv) * TMAX;
    outb = bext[G3 + sv];
  }
  const float ab0 = (lane < VOCAB)      ? bext[G3 + lane]      : 0.f;
  const float ab1 = (lane + 64 < VOCAB) ? bext[G3 + 64 + lane] : 0.f;

  // A-frag addressing: lane l reads A[row=l&15][k=(l>>4)*8+j]
  const int      arow = lane & 15;
  const unsigned ag   = (unsigned)((lane >> 4) << 4);
  const unsigned axor = ((unsigned)(arow & 7)) << 4;
  const char* ha = hab + (arow << 10);

  // wave-constant byte base: first tile of this wave's set, this k-half
  const char* const wbase = (const char*)wpk
      + (size_t)(wt * TPW) * 32768 + (size_t)half * 16384 + (size_t)lane * 16;

  for (int t = 0; t <= TMAX; ++t) {
    // ---------- A-frags for this wave's k-half (reused across 13 tiles) ----------
    bf16x8 afr0, afr1, afr2, afr3, afr4, afr5, afr6, afr7;
    {
      const unsigned kb = (unsigned)(half * 8);
      afr0 = *(const bf16x8*)(ha + ((((kb + 0) << 6) + ag) ^ axor));
      afr1 = *(const bf16x8*)(ha + ((((kb + 1) << 6) + ag) ^ axor));
      afr2 = *(const bf16x8*)(ha + ((((kb + 2) << 6) + ag) ^ axor));
      afr3 = *(const bf16x8*)(ha + ((((kb + 3) << 6) + ag) ^ axor));
      afr4 = *(const bf16x8*)(ha + ((((kb + 4) << 6) + ag) ^ axor));
      afr5 = *(const bf16x8*)(ha + ((((kb + 5) << 6) + ag) ^ axor));
      afr6 = *(const bf16x8*)(ha + ((((kb + 6) << 6) + ag) ^ axor));
      afr7 = *(const bf16x8*)(ha + ((((kb + 7) << 6) + ag) ^ axor));
    }

    // Last iteration: only logits tiles 96-103 matter; owned by tile-set 7.
    int tt0 = 0;
    bool active = true;
    if (t == TMAX) { if (wt == 7) tt0 = 5; else active = false; }

    if (active) {
      u32x4 qa0, qa1, qa2, qa3;               // chunk buffer A
      u32x4 qb0, qb1, qb2, qb3;               // chunk buffer B
      const char* bp = wbase + (size_t)tt0 * 32768;

      GLD4(qa0, qa1, qa2, qa3, bp);           // prologue: first tile, chunk 0

      for (int tt = tt0; tt < TPW; ++tt) {
        f32x4 acc = {0.f, 0.f, 0.f, 0.f};
        // chunk 0 in qa; issue chunk 1
        GLD4(qb0, qb1, qb2, qb3, bp + 4096);
        VMWAIT(4);
        MFMA4(acc, qa0, qa1, qa2, qa3, afr0, afr1);
        // chunk 1 in qb; issue chunk 2
        GLD4(qa0, qa1, qa2, qa3, bp + 8192);
        VMWAIT(4);
        MFMA4(acc, qb0, qb1, qb2, qb3, afr2, afr3);
        // chunk 2 in qa; issue chunk 3
        GLD4(qb0, qb1, qb2, qb3, bp + 12288);
        VMWAIT(4);
        MFMA4(acc, qa0, qa1, qa2, qa3, afr4, afr5);
        // chunk 3 in qb; issue next tile's chunk 0 (or drain at the end)
        if (tt + 1 < TPW) {
          GLD4(qa0, qa1, qa2, qa3, bp + 32768);
          VMWAIT(4);
        } else {
          VMWAIT(0);
        }
        MFMA4(acc, qb0, qb1, qb2, qb3, afr6, afr7);
        FOLDWRITE(acc, wt * TPW + tt);
        bp += 32768;
      }
    }
    __syncthreads();   // ghA+ghB (gates + logits) ready

    // ---------- logits out + wave-parallel argmax ----------
    if (t >= 1) {
      if (tid < ROWS * VOCAB) {
        float lg = ghA[sr][G3 + sv] + ghB[sr][G3 + sv] + outb;
        __builtin_nontemporal_store(lg, outp + (t - 1));
      }
      if (t < TMAX && wv < ROWS) {   // wave wv reduces row wv (first-max)
        float v0 = (lane < VOCAB)
                   ? ghA[wv][G3 + lane] + ghB[wv][G3 + lane] + ab0 : -1e30f;
        float v1 = (lane + 64 < VOCAB)
                   ? ghA[wv][G3 + 64 + lane] + ghB[wv][G3 + 64 + lane] + ab1 : -1e30f;
        float bv; int bi;
        if (v0 >= v1) { bv = v0; bi = lane; } else { bv = v1; bi = lane + 64; }
        #pragma unroll
        for (int off = 32; off >= 1; off >>= 1) {
          float ov = __shfl_xor(bv, off);
          int   oi = __shfl_xor(bi, off);
          if (ov > bv || (ov == bv && oi < bi)) { bv = ov; bi = oi; }
        }
        if (lane == 0) pred_lds[wv] = bi;
      }
    }
    __syncthreads();   // pred ready

    // ---------- gate nonlinearity + h update + split-bf16 writeback ----------
    if (t < TMAX) {
      #pragma unroll
      for (int rr = 0; rr < 4; ++rr) {
        int r = rb + rr;
        const float* eb = EIH + (size_t)pred_lds[r] * G3;
        float srg = eb[u]       + gbr + ghA[r][u]       + ghB[r][u];
        float szg = eb[HID + u] + gbz + ghA[r][HID + u] + ghB[r][HID + u];
        float hn  = ghA[r][2 * HID + u] + ghB[r][2 * HID + u] + gbn;
        float rg = 1.f / (1.f + expf(-srg));
        float zg = 1.f / (1.f + expf(-szg));
        float ng = tanhf(eb[2 * HID + u] + rg * hn);
        h[rr] = (1.f - zg) * ng + zg * h[rr];
        __bf16 hi = (__bf16)h[rr];
        __bf16 lo = (__bf16)(h[rr] - (float)hi);
        unsigned so = ((unsigned)(u * 2)) ^ (((unsigned)(r & 7)) << 4);
        *(__bf16*)(hab + (r << 10) + so)       = hi;
        *(__bf16*)(hab + ((r + 8) << 10) + so) = lo;
      }
    }
    __syncthreads();   // hab ready for next step
  }
}

extern "C" void kernel_launch(void* const* d_in, const int* in_sizes, int n_in,
                              void* d_out, int out_size, void* d_ws, size_t ws_size,
                              hipStream_t stream)
{
  const float* feat   = (const float*)d_in[0];
  const float* W_ih   = (const float*)d_in[1];
  const float* W_hh   = (const float*)d_in[2];
  const float* b_ih   = (const float*)d_in[3];
  const float* b_hh   = (const float*)d_in[4];
  const float* W_proj = (const float*)d_in[5];
  const float* b_proj = (const float*)d_in[6];
  const float* embed  = (const float*)d_in[7];
  const int*   sos    = (const int*)d_in[8];

  float*  wsf = (float*)d_ws;
  __bf16* wpk = (__bf16*)d_ws;
  float*  out = (float*)d_out;

  const int prep_total = SZ_WIHT + GEXT;
  prep_kernel<<<(prep_total + 255) / 256, 256, 0, stream>>>(W_ih, b_hh, b_proj, wsf);
  pack_kernel<<<(NT * 16 * 64 * 8 + 255) / 256, 256, 0, stream>>>(W_hh, W_proj, wpk);
  eih_kernel<<<600, 256, 0, stream>>>(embed, b_ih, wsf);
  decode_kernel<<<NWG, BLOCK, 0, stream>>>(feat, sos, wsf, wpk, out);
}

// Round 14
// 6047.235 us; speedup vs baseline: 7.9585x; 1.0495x over previous
//
#include <hip/hip_runtime.h>
#include <cmath>

#define HID   512
#define VOCAB 100
#define G3    1536            // 3*HID
#define GEXT  1664            // G3 + 100 logits + 28 pad (104 tiles of 16)
#define NT    104             // column tiles of 16
#define TMAX  201
#define ROWS  8
#define BLOCK 1024            // 16 waves: 8 tile-sets x 2 k-halves
#define NWG   256
#define TPW   13              // tiles per tile-set (104/8)
#define GHS   1672            // gh row stride (floats), ==8 mod 32 -> 2-way-free writes

typedef __bf16 bf16x8 __attribute__((ext_vector_type(8)));
typedef float  f32x4  __attribute__((ext_vector_type(4)));
typedef unsigned int u32x4 __attribute__((ext_vector_type(4)));

// ---- workspace layout ----
#define SZ_WPK   (NT * 16 * 2 * 64 * 8)   // bf16: packed B-fragments (3.4 MB)
#define FBASE    (SZ_WPK / 2)
#define OFF_EIH  FBASE                    // E_ih [100][1536] f32
#define SZ_EIH   (VOCAB * G3)
#define OFF_WIHT (OFF_EIH + SZ_EIH)       // W_ih^T [512][1536] f32
#define SZ_WIHT  (HID * G3)
#define OFF_BEXT (OFF_WIHT + SZ_WIHT)     // [b_hh | b_proj | pad] f32

__global__ void prep_kernel(const float* __restrict__ W_ih,
                            const float* __restrict__ b_hh,
                            const float* __restrict__ b_proj,
                            float* __restrict__ ws)
{
  int idx = blockIdx.x * 256 + threadIdx.x;
  if (idx < SZ_WIHT) {
    int k = idx / G3, j = idx - k * G3;
    ws[OFF_WIHT + idx] = W_ih[j * HID + k];
  } else if (idx < SZ_WIHT + GEXT) {
    int j = idx - SZ_WIHT;
    float v = 0.f;
    if (j < G3)              v = b_hh[j];
    else if (j < G3 + VOCAB) v = b_proj[j - G3];
    ws[OFF_BEXT + j] = v;
  }
}

// Pack W (= [W_hh rows | W_proj rows | 0]) into split-bf16 MFMA B-fragments.
// Byte offsets: tile*32768 + ks*2048 + (lo?1024:0) + lane*16.
__global__ void pack_kernel(const float* __restrict__ W_hh,
                            const float* __restrict__ W_proj,
                            __bf16* __restrict__ wpk)
{
  int idx = blockIdx.x * 256 + threadIdx.x;
  if (idx >= NT * 16 * 64 * 8) return;
  int j    = idx & 7;
  int lane = (idx >> 3) & 63;
  int ks   = (idx >> 9) & 15;
  int c    = idx >> 13;
  int col  = c * 16 + (lane & 15);
  int k    = ks * 32 + (lane >> 4) * 8 + j;
  float w = 0.f;
  if (col < G3)              w = W_hh[col * HID + k];
  else if (col < G3 + VOCAB) w = W_proj[(col - G3) * HID + k];
  __bf16 hi = (__bf16)w;
  __bf16 lo = (__bf16)(w - (float)hi);
  int base = (((c * 16 + ks) * 2) * 64 + lane) * 8 + j;
  wpk[base]       = hi;
  wpk[base + 512] = lo;
}

__global__ void eih_kernel(const float* __restrict__ embed,
                           const float* __restrict__ b_ih,
                           float* __restrict__ ws)
{
  int v = blockIdx.x / 6;
  int j = (blockIdx.x % 6) * 256 + threadIdx.x;
  const float* WihT = ws + OFF_WIHT;
  const float* e = embed + v * HID;
  float acc = b_ih[j];
  for (int k = 0; k < HID; ++k)
    acc = fmaf(WihT[k * G3 + j], e[k], acc);
  ws[OFF_EIH + v * G3 + j] = acc;
}

// ---- inline-asm B-stream pipeline primitives ----
// "=&v" EARLY-CLOBBER is load-bearing (round-11 crash: async-written outputs
// must not alias the address pair %4).
#define GLD4(F0, F1, F2, F3, P)                                   \
  asm volatile("global_load_dwordx4 %0, %4, off\n\t"              \
               "global_load_dwordx4 %1, %4, off offset:1024\n\t"  \
               "global_load_dwordx4 %2, %4, off offset:2048\n\t"  \
               "global_load_dwordx4 %3, %4, off offset:3072"      \
               : "=&v"(F0), "=&v"(F1), "=&v"(F2), "=&v"(F3)       \
               : "v"(P))

// Counted wait + scheduling fence (rule #18: MFMA must not hoist above it).
#define VMWAIT(N)                                 \
  do { asm volatile("s_waitcnt vmcnt(" #N ")");   \
       __builtin_amdgcn_sched_barrier(0); } while (0)

#define BC(X) __builtin_bit_cast(bf16x8, X)

// 4 MFMAs: one chunk (2 k-steps, hi then lo) — exact round-7 operand order.
#define MFMA4(ACC, Q0, Q1, Q2, Q3, A0, A1)                                      \
  do {                                                                          \
    ACC = __builtin_amdgcn_mfma_f32_16x16x32_bf16(A0, BC(Q0), ACC, 0, 0, 0);    \
    ACC = __builtin_amdgcn_mfma_f32_16x16x32_bf16(A0, BC(Q1), ACC, 0, 0, 0);    \
    ACC = __builtin_amdgcn_mfma_f32_16x16x32_bf16(A1, BC(Q2), ACC, 0, 0, 0);    \
    ACC = __builtin_amdgcn_mfma_f32_16x16x32_bf16(A1, BC(Q3), ACC, 0, 0, 0);    \
  } while (0)

// Fold H_lo rows (8-15, lanes 32-63) into H_hi rows and write one gh stripe.
#define FOLDWRITE(ACC, TILE)                                      \
  do {                                                            \
    int colw_ = (TILE) * 16 + (lane & 15);                        \
    float vs_[4];                                                 \
    _Pragma("unroll")                                             \
    for (int i_ = 0; i_ < 4; ++i_)                                \
      vs_[i_] = ACC[i_] + __shfl_xor(ACC[i_], 32, 64);            \
    if (lane < 32) {                                              \
      int r0_ = (lane >> 4) * 4;                                  \
      _Pragma("unroll")                                           \
      for (int i_ = 0; i_ < 4; ++i_)                              \
        ghW[r0_ + i_][colw_] = vs_[i_];                           \
    }                                                             \
  } while (0)

// fast sigmoid / tanh (v_exp_f32 + rcp; ~1 ulp, overflow-safe)
__device__ __forceinline__ float fsigm(float x) {
  return __builtin_amdgcn_rcpf(1.f + __expf(-x));
}
__device__ __forceinline__ float ftanh(float x) {
  float e2 = __expf(-2.f * fabsf(x));            // in (0,1]: no overflow
  float t  = (1.f - e2) * __builtin_amdgcn_rcpf(1.f + e2);
  return copysignf(t, x);
}

// Persistent GRU decode: 8 rows/block, 256 blocks, 16 waves (8 tile-sets x 2
// k-halves -> ghA/ghB partials). B-stream: inline-asm chunk pipeline,
// steady-state vmcnt(4). NEW vs round 12: (1) per-block tile-order rotation
// (blockIdx%13) to desync the barrier-locked L2 same-line sweeps across CUs;
// (2) wave-redundant register argmax (each wave only needs its own 4 rows)
// -> 2 barriers/step instead of 3; (3) v_exp_f32-based gate transcendentals.
__global__ __launch_bounds__(BLOCK) void decode_kernel(
    const float* __restrict__ feat,
    const int* __restrict__ sos,
    const float* __restrict__ ws,
    const __bf16* __restrict__ wpk,
    float* __restrict__ out)
{
  __shared__ __align__(16) char hab[16 * 1024];   // rows 0-7 hi, 8-15 lo; XOR-swizzled
  __shared__ float ghA[ROWS][GHS];                // k-half 0 partials
  __shared__ float ghB[ROWS][GHS];                // k-half 1 partials

  const float* __restrict__ EIH  = ws + OFF_EIH;
  const float* __restrict__ bext = ws + OFF_BEXT;

  const int tid  = threadIdx.x;
  const int lane = tid & 63;
  const int wv   = tid >> 6;          // wave 0..15
  const int half = wv >> 3;           // k-half 0/1
  const int wt   = wv & 7;            // tile-set 0..7
  const int b0   = blockIdx.x * ROWS;
  const int u    = tid & (HID - 1);   // unit 0..511
  const int rb   = (tid >> 9) * 4;    // row base 0 or 4 (wave-uniform)
  const int rot  = blockIdx.x % TPW;  // per-block tile-order rotation

  float (*ghW)[GHS] = half ? ghB : ghA;

  // ---- init: h in regs (4 rows per thread), split-bf16 into hab ----
  float h[4];
  int   pred[4];
  #pragma unroll
  for (int rr = 0; rr < 4; ++rr) {
    int r = rb + rr;
    float f = feat[(size_t)(b0 + r) * HID + u];
    h[rr] = f;
    pred[rr] = sos[0];
    __bf16 hi = (__bf16)f;
    __bf16 lo = (__bf16)(f - (float)hi);
    unsigned so = ((unsigned)(u * 2)) ^ (((unsigned)(r & 7)) << 4);
    *(__bf16*)(hab + (r << 10) + so)       = hi;
    *(__bf16*)(hab + ((r + 8) << 10) + so) = lo;
  }
  __syncthreads();

  // per-thread consumer biases
  const float gbr = bext[u], gbz = bext[HID + u], gbn = bext[2 * HID + u];
  const int sr = tid / VOCAB, sv = tid - sr * VOCAB;
  float* outp = nullptr; float outb = 0.f;
  if (tid < ROWS * VOCAB) {
    outp = out + ((size_t)(b0 + sr) * VOCAB + sv) * TMAX;
    outb = bext[G3 + sv];
  }
  const float ab0 = (lane < VOCAB)      ? bext[G3 + lane]      : 0.f;
  const float ab1 = (lane + 64 < VOCAB) ? bext[G3 + 64 + lane] : 0.f;

  // A-frag addressing: lane l reads A[row=l&15][k=(l>>4)*8+j]
  const int      arow = lane & 15;
  const unsigned ag   = (unsigned)((lane >> 4) << 4);
  const unsigned axor = ((unsigned)(arow & 7)) << 4;
  const char* ha = hab + (arow << 10);

  // wave-constant byte base: first tile of this wave's set, this k-half
  const char* const wbase = (const char*)wpk
      + (size_t)(wt * TPW) * 32768 + (size_t)half * 16384 + (size_t)lane * 16;

  for (int t = 0; t <= TMAX; ++t) {
    // ---------- A-frags for this wave's k-half (reused across 13 tiles) ----------
    bf16x8 afr0, afr1, afr2, afr3, afr4, afr5, afr6, afr7;
    {
      const unsigned kb = (unsigned)(half * 8);
      afr0 = *(const bf16x8*)(ha + ((((kb + 0) << 6) + ag) ^ axor));
      afr1 = *(const bf16x8*)(ha + ((((kb + 1) << 6) + ag) ^ axor));
      afr2 = *(const bf16x8*)(ha + ((((kb + 2) << 6) + ag) ^ axor));
      afr3 = *(const bf16x8*)(ha + ((((kb + 3) << 6) + ag) ^ axor));
      afr4 = *(const bf16x8*)(ha + ((((kb + 4) << 6) + ag) ^ axor));
      afr5 = *(const bf16x8*)(ha + ((((kb + 5) << 6) + ag) ^ axor));
      afr6 = *(const bf16x8*)(ha + ((((kb + 6) << 6) + ag) ^ axor));
      afr7 = *(const bf16x8*)(ha + ((((kb + 7) << 6) + ag) ^ axor));
    }

    // Last iteration: only logits tiles 96-103 matter (tile-set 7, tt 5..12).
    int tstart = 0, rot_eff = rot;
    bool active = true;
    if (t == TMAX) { if (wt == 7) { tstart = 5; rot_eff = 0; } else active = false; }

    if (active) {
      u32x4 qa0, qa1, qa2, qa3;               // chunk buffer A
      u32x4 qb0, qb1, qb2, qb3;               // chunk buffer B
      int tl = tstart + rot_eff; if (tl >= TPW) tl -= TPW;
      const char* bp = wbase + (size_t)tl * 32768;

      GLD4(qa0, qa1, qa2, qa3, bp);           // prologue: first tile, chunk 0

      for (int tt = tstart; tt < TPW; ++tt) {
        f32x4 acc = {0.f, 0.f, 0.f, 0.f};
        GLD4(qb0, qb1, qb2, qb3, bp + 4096);
        VMWAIT(4);
        MFMA4(acc, qa0, qa1, qa2, qa3, afr0, afr1);
        GLD4(qa0, qa1, qa2, qa3, bp + 8192);
        VMWAIT(4);
        MFMA4(acc, qb0, qb1, qb2, qb3, afr2, afr3);
        GLD4(qb0, qb1, qb2, qb3, bp + 12288);
        VMWAIT(4);
        MFMA4(acc, qa0, qa1, qa2, qa3, afr4, afr5);
        int tln = tl + 1; if (tln >= TPW) tln -= TPW;
        const char* bpn = wbase + (size_t)tln * 32768;
        if (tt + 1 < TPW) {
          GLD4(qa0, qa1, qa2, qa3, bpn);      // next tile's chunk 0 (rotated order)
          VMWAIT(4);
        } else {
          VMWAIT(0);
        }
        MFMA4(acc, qb0, qb1, qb2, qb3, afr6, afr7);
        FOLDWRITE(acc, wt * TPW + tl);
        bp = bpn; tl = tln;
      }
    }
    __syncthreads();   // barrier 1: ghA+ghB (gates + logits) ready

    // ---------- logits out + wave-redundant register argmax ----------
    if (t >= 1) {
      if (tid < ROWS * VOCAB) {
        float lg = ghA[sr][G3 + sv] + ghB[sr][G3 + sv] + outb;
        __builtin_nontemporal_store(lg, outp + (t - 1));
      }
      if (t < TMAX) {
        #pragma unroll
        for (int rr = 0; rr < 4; ++rr) {   // each wave: its own 4 rows only
          int row = rb + rr;
          float v0 = (lane < VOCAB)
                     ? ghA[row][G3 + lane] + ghB[row][G3 + lane] + ab0 : -1e30f;
          float v1 = (lane + 64 < VOCAB)
                     ? ghA[row][G3 + 64 + lane] + ghB[row][G3 + 64 + lane] + ab1 : -1e30f;
          float bv; int bi;
          if (v0 >= v1) { bv = v0; bi = lane; } else { bv = v1; bi = lane + 64; }
          #pragma unroll
          for (int off = 32; off >= 1; off >>= 1) {
            float ov = __shfl_xor(bv, off);
            int   oi = __shfl_xor(bi, off);
            if (ov > bv || (ov == bv && oi < bi)) { bv = ov; bi = oi; }
          }
          pred[rr] = bi;                   // uniform across lanes; first-max kept
        }
      }
    }
    // no barrier: pred is in registers, each wave uses only its own rows

    // ---------- gate nonlinearity + h update + split-bf16 writeback ----------
    if (t < TMAX) {
      #pragma unroll
      for (int rr = 0; rr < 4; ++rr) {
        int r = rb + rr;
        const float* eb = EIH + (size_t)pred[rr] * G3;
        float srg = eb[u]       + gbr + ghA[r][u]       + ghB[r][u];
        float szg = eb[HID + u] + gbz + ghA[r][HID + u] + ghB[r][HID + u];
        float hn  = ghA[r][2 * HID + u] + ghB[r][2 * HID + u] + gbn;
        float rg = fsigm(srg);
        float zg = fsigm(szg);
        float ng = ftanh(eb[2 * HID + u] + rg * hn);
        h[rr] = (1.f - zg) * ng + zg * h[rr];
        __bf16 hi = (__bf16)h[rr];
        __bf16 lo = (__bf16)(h[rr] - (float)hi);
        unsigned so = ((unsigned)(u * 2)) ^ (((unsigned)(r & 7)) << 4);
        *(__bf16*)(hab + (r << 10) + so)       = hi;
        *(__bf16*)(hab + ((r + 8) << 10) + so) = lo;
      }
    }
    __syncthreads();   // barrier 2: hab ready for next step
  }
}

extern "C" void kernel_launch(void* const* d_in, const int* in_sizes, int n_in,
                              void* d_out, int out_size, void* d_ws, size_t ws_size,
                              hipStream_t stream)
{
  const float* feat   = (const float*)d_in[0];
  const float* W_ih   = (const float*)d_in[1];
  const float* W_hh   = (const float*)d_in[2];
  const float* b_ih   = (const float*)d_in[3];
  const float* b_hh   = (const float*)d_in[4];
  const float* W_proj = (const float*)d_in[5];
  const float* b_proj = (const float*)d_in[6];
  const float* embed  = (const float*)d_in[7];
  const int*   sos    = (const int*)d_in[8];

  float*  wsf = (float*)d_ws;
  __bf16* wpk = (__bf16*)d_ws;
  float*  out = (float*)d_out;

  const int prep_total = SZ_WIHT + GEXT;
  prep_kernel<<<(prep_total + 255) / 256, 256, 0, stream>>>(W_ih, b_hh, b_proj, wsf);
  pack_kernel<<<(NT * 16 * 64 * 8 + 255) / 256, 256, 0, stream>>>(W_hh, W_proj, wpk);
  eih_kernel<<<600, 256, 0, stream>>>(embed, b_ih, wsf);
  decode_kernel<<<NWG, BLOCK, 0, stream>>>(feat, sos, wsf, wpk, out);
}